// Round 3
// baseline (246.860 us; speedup 1.0000x reference)
//
#include <hip/hip_runtime.h>
#include <stdint.h>

// Problem constants
#define E_DIM 256
#define HEADS 8
#define NQ 49
#define S_TOT 196      // 14*14
#define NROIS 512
#define FH 152
#define FW 256
#define HW_TOT (FH*FW) // 38912

// LDS strides (u16 units)
#define KA_ST 228      // attn [64][228]; kh aliased inside same region with stride 36
#define KH_ST 36
#define VT_ST 228
#define OR_ST 36
#define AS_ST 260
#define PS_ST 260

typedef unsigned short u16;
typedef short bf16x8 __attribute__((ext_vector_type(8)));
typedef float f32x4 __attribute__((ext_vector_type(4)));
typedef unsigned short us8 __attribute__((ext_vector_type(8)));

#define MFMA(a,b,c) __builtin_amdgcn_mfma_f32_16x16x32_bf16((a),(b),(c),0,0,0)

__device__ __forceinline__ u16 f2bf(float f) {
  union { float f; uint32_t u; } v; v.f = f;
  uint32_t u = v.u;
  return (u16)((u + 0x7FFFu + ((u >> 16) & 1u)) >> 16);
}
__device__ __forceinline__ float bf2f(u16 h) {
  union { uint32_t u; float f; } v; v.u = ((uint32_t)h) << 16;
  return v.f;
}
__device__ __forceinline__ bf16x8 ld_frag(const u16* p) {   // 2x ds_read_b64
  union { uint2 d[2]; bf16x8 v; } t;
  t.d[0] = *(const uint2*)(p);
  t.d[1] = *(const uint2*)(p + 4);
  return t.v;
}
__device__ __forceinline__ bf16x8 ld_frag_g(const u16* p) { // 16B global
  union { uint4 d; bf16x8 v; } t;
  t.d = *(const uint4*)(p);
  return t.v;
}
__device__ __forceinline__ ushort4 pack4(float a, float b, float c, float d) {
  ushort4 r; r.x = f2bf(a); r.y = f2bf(b); r.z = f2bf(c); r.w = f2bf(d); return r;
}

// ---------------- K0: transpose/convert features + convert weights + qs ----------------
// blocks [0,2432): fT tiles; [2432,2688): weight convert; [2688,2696): qs
__global__ __launch_bounds__(256) void prep_all(
    const float* __restrict__ f, const float* __restrict__ ipw,
    const float* __restrict__ opw, const float* __restrict__ ipb,
    const float* __restrict__ cq,
    u16* __restrict__ fT, u16* __restrict__ Wk, u16* __restrict__ Wv,
    u16* __restrict__ Wo, u16* __restrict__ qs)
{
  const int b = blockIdx.x;
  const int t = threadIdx.x;
  if (b < 2432) {
    __shared__ float tile[64][69];     // 69: <=2-way banks both phases
    const int hw0 = (b >> 2) << 6;
    const int c0 = (b & 3) << 6;
#pragma unroll
    for (int i = 0; i < 4; ++i) {
      int c_l = (t >> 4) + (i << 4);
      int hw_l = (t & 15) << 2;
      float4 v = *(const float4*)(f + (size_t)(c0 + c_l)*HW_TOT + hw0 + hw_l);
      tile[c_l][hw_l] = v.x; tile[c_l][hw_l+1] = v.y;
      tile[c_l][hw_l+2] = v.z; tile[c_l][hw_l+3] = v.w;
    }
    __syncthreads();
    const int hw_l = t >> 2;
    const int cc = (t & 3) << 4;
    u16 tmp[16];
#pragma unroll
    for (int m = 0; m < 16; ++m) tmp[m] = f2bf(tile[cc + m][hw_l]);
    u16* dst = fT + (size_t)(hw0 + hw_l)*256 + c0 + cc;
    *(us8*)(dst)     = *(const us8*)(tmp);
    *(us8*)(dst + 8) = *(const us8*)(tmp + 8);
  } else if (b < 2688) {
    int i = ((b - 2432) << 8) + t;
    Wk[i] = f2bf(ipw[65536 + i]);
    Wv[i] = f2bf(ipw[131072 + i]);
    Wo[i] = f2bf(opw[i]);
  } else {
    int h = b - 2688;
    for (int r = 0; r < 8; ++r) {
      int o = t + 256*r;
      int qq = o >> 5, d = o & 31;
      float acc = 0.f;
      if (qq < NQ) {
        acc = ipb[h*32 + d];
        const float4* wr = (const float4*)(ipw + (size_t)(h*32 + d)*256);
        const float4* cr = (const float4*)(cq + (size_t)qq*256);
        float s = 0.f;
        for (int e = 0; e < 64; ++e) {
          float4 a = cr[e], bb = wr[e];
          s += a.x*bb.x + a.y*bb.y + a.z*bb.z + a.w*bb.w;
        }
        acc = (acc + s) * 0.17677669529663687f;   // 1/sqrt(32)
      }
      qs[h*2048 + o] = f2bf(acc);
    }
  }
}

// ---------------- K1: fK/fV = fT @ W^T (A-frags straight from global bf16) ----------------
// 512 threads, 8 waves: wave = (map = w>>2, n-quarter = w&3). 64 m x 64 n per wave.
__global__ __launch_bounds__(512) void proj_kv(
    const u16* __restrict__ fT, const u16* __restrict__ Wk, const u16* __restrict__ Wv,
    u16* __restrict__ fK, u16* __restrict__ fV)
{
  const int m0 = blockIdx.x << 6;
  const int t = threadIdx.x;
  const int lane = t & 63;
  const int w = t >> 6;
  const int g = lane >> 4, l15 = lane & 15;
  const u16* W = (w >> 2) ? Wv : Wk;
  u16* dst = (w >> 2) ? fV : fK;
  const int nq = (w & 3) << 6;
  f32x4 acc[4][4];
#pragma unroll
  for (int mf = 0; mf < 4; ++mf)
#pragma unroll
    for (int nt = 0; nt < 4; ++nt) acc[mf][nt] = (f32x4){0.f,0.f,0.f,0.f};

  for (int kt = 0; kt < 8; ++kt) {
    bf16x8 a[4], bb[4];
#pragma unroll
    for (int mf = 0; mf < 4; ++mf)
      a[mf] = ld_frag_g(fT + (size_t)(m0 + (mf << 4) + l15)*256 + (kt << 5) + (g << 3));
#pragma unroll
    for (int nt = 0; nt < 4; ++nt)
      bb[nt] = ld_frag_g(W + (size_t)(nq + (nt << 4) + l15)*256 + (kt << 5) + (g << 3));
#pragma unroll
    for (int mf = 0; mf < 4; ++mf)
#pragma unroll
      for (int nt = 0; nt < 4; ++nt)
        acc[mf][nt] = MFMA(a[mf], bb[nt], acc[mf][nt]);
  }
#pragma unroll
  for (int mf = 0; mf < 4; ++mf)
#pragma unroll
    for (int nt = 0; nt < 4; ++nt)
#pragma unroll
      for (int i = 0; i < 4; ++i)
        dst[(size_t)(m0 + (mf << 4) + (g << 2) + i)*256 + nq + (nt << 4) + l15] =
            f2bf(acc[mf][nt][i]);
}

// ---------------- K2: main fused kernel, one ROI per block, 3 blocks/CU ----------------
struct SMemA {
  u16 ka[64][KA_ST];      // 29,184 B  attn [q][s]; kh [s][32] aliased at stride 36
  u16 vT[32][VT_ST];      // 14,592 B  v^T [d][s], cols 196..227 region: 196..223 zeroed
  u16 ore[64][OR_ST];     //  4,608 B  per-head o redistribution
};                         // 48,384 B
struct SMemC {
  u16 ast[NQ][AS_ST];     // 25,480 B
  u16 pos[NQ][PS_ST];     // 25,480 B
};                         // 50,960 B
union SMem { SMemA a; SMemC c; };   // 50,960 B -> 3 blocks/CU

__global__ __launch_bounds__(256, 3) void fused_roi_attn(
    const float* __restrict__ rois,
    const float* __restrict__ balance_p,
    const float* __restrict__ bv,       // in_proj_bias + 512
    const float* __restrict__ bout,
    const u16*  __restrict__ fT,
    const u16*  __restrict__ fK,
    const u16*  __restrict__ fV,
    const u16*  __restrict__ Woutbf,
    const u16*  __restrict__ qsPad,     // [8][64][32]
    float* __restrict__ out)            // [512][256][49]
{
  __shared__ SMem sm;
  u16* kh = &sm.a.ka[0][0];            // kh[s*36 + d]
  const int tid = threadIdx.x;
  const int lane = tid & 63;
  const int w = tid >> 6;
  const int g = lane >> 4;
  const int l15 = lane & 15;
  const int n = blockIdx.x;

  // ---- ROI scalars + per-thread register sampling params (2 s-values/thread) ----
  float x1 = rois[n*5 + 1], y1r = rois[n*5 + 2], x2 = rois[n*5 + 3], y2 = rois[n*5 + 4];
  const float sc = 1.0f/16.0f;
  float sx = x1*sc - 0.5f, sy = y1r*sc - 0.5f;
  float bw = (x2 - x1)*sc*(1.0f/14.0f);
  float bh = (y2 - y1r)*sc*(1.0f/14.0f);

  int   pb[2], po01[2], po10[2];
  float pw0[2], pw1[2], pw2[2], pw3[2];
#pragma unroll
  for (int u = 0; u < 2; ++u) {
    int s = (tid >> 1) + (u << 7);
    if (s < S_TOT) {
      int gy = s/14, gx = s - gy*14;
      float y = sy + ((float)gy + 0.5f)*bh;
      float x = sx + ((float)gx + 0.5f)*bw;
      float valid = (y >= -1.0f && y <= (float)FH && x >= -1.0f && x <= (float)FW) ? 1.0f : 0.0f;
      float yc = fminf(fmaxf(y, 0.0f), (float)(FH-1));
      float xc = fminf(fmaxf(x, 0.0f), (float)(FW-1));
      float y0f = floorf(yc), x0f = floorf(xc);
      int y0 = (int)y0f, x0 = (int)x0f;
      float ly = yc - y0f, lx = xc - x0f;
      float hy = 1.0f - ly, hx = 1.0f - lx;
      pb[u]   = (y0*FW + x0) << 8;                 // pre-scaled by 256 ch
      po01[u] = ((x0 + 1 < FW) ? 1 : 0) << 8;
      po10[u] = ((y0 + 1 < FH) ? FW : 0) << 8;
      pw0[u] = hy*hx*valid; pw1[u] = hy*lx*valid;
      pw2[u] = ly*hx*valid; pw3[u] = ly*lx*valid;
    }
  }

  // vT pad cols 196..223 zero (persist: sampling writes only cols <196)
  for (int i = tid; i < 32*28; i += 256) { int r = i/28; sm.a.vT[r][196 + (i - r*28)] = 0; }

  float bal;
  { float bp = balance_p[0]; bal = fminf(fmaxf(bp*(1.0f/6.0f) + 0.5f, 0.0f), 1.0f); }

  f32x4 attacc[16];
#pragma unroll
  for (int i = 0; i < 16; ++i) attacc[i] = (f32x4){0.f,0.f,0.f,0.f};

  for (int h = 0; h < HEADS; ++h) {
    __syncthreads();   // T: prior-head attn/vT reads done; region writable

    // ---- sample k_h -> kh[s][32], v_h -> vT[d][s] ----
#pragma unroll
    for (int u = 0; u < 2; ++u) {
      int s = (tid >> 1) + (u << 7);
      if (s < S_TOT) {
        int hf = tid & 1;
        int base = pb[u] + (h << 5) + (hf << 4);
        int o01 = po01[u], o10 = po10[u], o11 = o01 + o10;
        float w0 = pw0[u], w1 = pw1[u], w2 = pw2[u], w3 = pw3[u];
        const u16* pk = fK + base;
        const u16* pv = fV + base;
        us8 k00a = *(const us8*)(pk);       us8 k00b = *(const us8*)(pk + 8);
        us8 k01a = *(const us8*)(pk + o01); us8 k01b = *(const us8*)(pk + o01 + 8);
        us8 k10a = *(const us8*)(pk + o10); us8 k10b = *(const us8*)(pk + o10 + 8);
        us8 k11a = *(const us8*)(pk + o11); us8 k11b = *(const us8*)(pk + o11 + 8);
        us8 v00a = *(const us8*)(pv);       us8 v00b = *(const us8*)(pv + 8);
        us8 v01a = *(const us8*)(pv + o01); us8 v01b = *(const us8*)(pv + o01 + 8);
        us8 v10a = *(const us8*)(pv + o10); us8 v10b = *(const us8*)(pv + o10 + 8);
        us8 v11a = *(const us8*)(pv + o11); us8 v11b = *(const us8*)(pv + o11 + 8);
        float kk[16], vv[16];
#pragma unroll
        for (int c = 0; c < 8; ++c) {
          kk[c]   = w0*bf2f(k00a[c]) + w1*bf2f(k01a[c]) + w2*bf2f(k10a[c]) + w3*bf2f(k11a[c]);
          kk[c+8] = w0*bf2f(k00b[c]) + w1*bf2f(k01b[c]) + w2*bf2f(k10b[c]) + w3*bf2f(k11b[c]);
          vv[c]   = w0*bf2f(v00a[c]) + w1*bf2f(v01a[c]) + w2*bf2f(v10a[c]) + w3*bf2f(v11a[c]);
          vv[c+8] = w0*bf2f(v00b[c]) + w1*bf2f(v01b[c]) + w2*bf2f(v10b[c]) + w3*bf2f(v11b[c]);
        }
        u16* krow = kh + s*KH_ST + (hf << 4);
        *(ushort4*)(krow)      = pack4(kk[0],  kk[1],  kk[2],  kk[3]);
        *(ushort4*)(krow + 4)  = pack4(kk[4],  kk[5],  kk[6],  kk[7]);
        *(ushort4*)(krow + 8)  = pack4(kk[8],  kk[9],  kk[10], kk[11]);
        *(ushort4*)(krow + 12) = pack4(kk[12], kk[13], kk[14], kk[15]);
#pragma unroll
        for (int j = 0; j < 16; ++j) sm.a.vT[(hf << 4) + j][s] = f2bf(vv[j]);
      }
    }
    __syncthreads();   // S: kh, vT ready

    // ---- logits[q=16w+4g+i][s=16nt+l15] ----
    bf16x8 aq = ld_frag_g(qsPad + (size_t)((h << 6) + (w << 4) + l15)*32 + (g << 3));
    f32x4 lac[13];
#pragma unroll
    for (int nt = 0; nt < 13; ++nt) {
      bf16x8 bk = ld_frag(kh + ((nt << 4) + l15)*KH_ST + (g << 3));
      f32x4 z = (f32x4){0.f,0.f,0.f,0.f};
      lac[nt] = MFMA(aq, bk, z);
    }
    if (l15 >= 4) {      // mask s >= 196 (kills any NaN from garbage kh rows too)
#pragma unroll
      for (int i = 0; i < 4; ++i) lac[12][i] = -1e30f;
    }
    // ---- softmax over s ----
    float srow[4];
#pragma unroll
    for (int i = 0; i < 4; ++i) {
      float m = lac[0][i];
#pragma unroll
      for (int nt = 1; nt < 13; ++nt) m = fmaxf(m, lac[nt][i]);
#pragma unroll
      for (int off = 1; off < 16; off <<= 1) m = fmaxf(m, __shfl_xor(m, off, 64));
      float sumv = 0.f;
#pragma unroll
      for (int nt = 0; nt < 13; ++nt) {
        float p = __expf(lac[nt][i] - m);
        lac[nt][i] = p; sumv += p;
      }
#pragma unroll
      for (int off = 1; off < 16; off <<= 1) sumv += __shfl_xor(sumv, off, 64);
      srow[i] = 1.0f / sumv;
    }
    __syncthreads();   // L: all kh reads done; attn may overwrite region

    // attn writes (wave-local rows) + re-zero pad cols 208..223 (clobbered by kh)
#pragma unroll
    for (int nt = 0; nt < 13; ++nt)
#pragma unroll
      for (int i = 0; i < 4; ++i)
        sm.a.ka[(w << 4) + (g << 2) + i][(nt << 4) + l15] = f2bf(lac[nt][i]*srow[i]);
    *(ushort4*)(&sm.a.ka[tid >> 2][208 + ((tid & 3) << 2)]) = (ushort4){0,0,0,0};

    // ---- PV: o_h = attn @ v (attn rows wave-local; vT stable since bar S) ----
    f32x4 o0 = (f32x4){0.f,0.f,0.f,0.f}, o1 = (f32x4){0.f,0.f,0.f,0.f};
#pragma unroll
    for (int kt = 0; kt < 7; ++kt) {
      bf16x8 ap = ld_frag(&sm.a.ka[(w << 4) + l15][(kt << 5) + (g << 3)]);
      bf16x8 b0 = ld_frag(&sm.a.vT[l15][(kt << 5) + (g << 3)]);
      bf16x8 b1 = ld_frag(&sm.a.vT[16 + l15][(kt << 5) + (g << 3)]);
      o0 = MFMA(ap, b0, o0);
      o1 = MFMA(ap, b1, o1);
    }
    // bias (bv commutes through softmax) + redistribute to A-frag layout (wave-local)
    float bv0 = bv[(h << 5) + l15];
    float bv1 = bv[(h << 5) + 16 + l15];
#pragma unroll
    for (int i = 0; i < 4; ++i) {
      sm.a.ore[(w << 4) + (g << 2) + i][l15]      = f2bf(o0[i] + bv0);
      sm.a.ore[(w << 4) + (g << 2) + i][16 + l15] = f2bf(o1[i] + bv1);
    }
    // ---- out-projection K-split accumulate ----
    bf16x8 ao = ld_frag(&sm.a.ore[(w << 4) + l15][g << 3]);
#pragma unroll
    for (int nt = 0; nt < 16; ++nt) {
      bf16x8 bo = ld_frag_g(Woutbf + (size_t)((nt << 4) + l15)*256 + (h << 5) + (g << 3));
      attacc[nt] = MFMA(ao, bo, attacc[nt]);
    }
  } // heads

  // ---- Phase C ----
  __syncthreads();   // all A-region reads done before aliasing ast/pos
#pragma unroll
  for (int nt = 0; nt < 16; ++nt) {
    float bo = bout[(nt << 4) + l15];
#pragma unroll
    for (int i = 0; i < 4; ++i) {
      int r = (w << 4) + (g << 2) + i;
      if (r < NQ) sm.c.ast[r][(nt << 4) + l15] = f2bf(attacc[nt][i] + bo);
    }
  }
  // pos[q][c]: 4-point avg of bilinear samples at the 14x14 grid (params recomputed)
  for (int it = 0; it < 13; ++it) {
    int item = tid + (it << 8);
    if (item < NQ*64) {
      int q = item >> 6, cg = item & 63;
      int oy = q/7, ox = q - oy*7;
      float a0 = 0.f, a1 = 0.f, a2 = 0.f, a3 = 0.f;
#pragma unroll
      for (int jj = 0; jj < 2; ++jj)
#pragma unroll
        for (int ii = 0; ii < 2; ++ii) {
          int gy = (oy << 1) + jj, gx = (ox << 1) + ii;
          float y = sy + ((float)gy + 0.5f)*bh;
          float x = sx + ((float)gx + 0.5f)*bw;
          float valid = (y >= -1.0f && y <= (float)FH && x >= -1.0f && x <= (float)FW) ? 1.0f : 0.0f;
          float yc = fminf(fmaxf(y, 0.0f), (float)(FH-1));
          float xc = fminf(fmaxf(x, 0.0f), (float)(FW-1));
          float y0f = floorf(yc), x0f = floorf(xc);
          int y0 = (int)y0f, x0 = (int)x0f;
          int o01 = ((x0 + 1 < FW) ? 1 : 0) << 8;
          int o10 = ((y0 + 1 < FH) ? FW : 0) << 8;
          float ly = yc - y0f, lx = xc - x0f;
          float hy = 1.0f - ly, hx = 1.0f - lx;
          float w0 = hy*hx*valid, w1 = hy*lx*valid, w2 = ly*hx*valid, w3 = ly*lx*valid;
          const u16* pt = fT + (((size_t)(y0*FW + x0)) << 8) + (cg << 2);
          ushort4 c00 = *(const ushort4*)(pt);
          ushort4 c01 = *(const ushort4*)(pt + o01);
          ushort4 c10 = *(const ushort4*)(pt + o10);
          ushort4 c11 = *(const ushort4*)(pt + o10 + o01);
          a0 += w0*bf2f(c00.x) + w1*bf2f(c01.x) + w2*bf2f(c10.x) + w3*bf2f(c11.x);
          a1 += w0*bf2f(c00.y) + w1*bf2f(c01.y) + w2*bf2f(c10.y) + w3*bf2f(c11.y);
          a2 += w0*bf2f(c00.z) + w1*bf2f(c01.z) + w2*bf2f(c10.z) + w3*bf2f(c11.z);
          a3 += w0*bf2f(c00.w) + w1*bf2f(c01.w) + w2*bf2f(c10.w) + w3*bf2f(c11.w);
        }
      *(ushort4*)(&sm.c.pos[q][cg << 2]) = pack4(0.25f*a0, 0.25f*a1, 0.25f*a2, 0.25f*a3);
    }
  }
  __syncthreads();
  float ibal = 1.0f - bal;
  float* outp = out + (size_t)n*(E_DIM*NQ);
  for (int j = 0; j < 49; ++j) {
    int idx = (j << 8) + tid;        // 12544 = 49*256 exactly
    int eo = idx/49;
    int q  = idx - eo*49;
    outp[idx] = bal*bf2f(sm.c.pos[q][eo]) + ibal*bf2f(sm.c.ast[q][eo]);
  }
}

// ---------------- launcher ----------------
// ws: fT | fK | fV (19,922,944 B each) | Wk | Wv | Wo (131,072 each) | qs 32,768
extern "C" void kernel_launch(void* const* d_in, const int* in_sizes, int n_in,
                              void* d_out, int out_size, void* d_ws, size_t ws_size,
                              hipStream_t stream) {
  const float* features = (const float*)d_in[0];
  const float* rois     = (const float*)d_in[1];
  const float* cq       = (const float*)d_in[2];
  const float* ipw      = (const float*)d_in[3];
  const float* ipb      = (const float*)d_in[4];
  const float* opw      = (const float*)d_in[5];
  const float* opb      = (const float*)d_in[6];
  const float* balp     = (const float*)d_in[7];
  float* out = (float*)d_out;

  char* ws = (char*)d_ws;
  const size_t FMB = (size_t)HW_TOT*256*2;   // 19,922,944
  u16* fT = (u16*)ws;
  u16* fK = (u16*)(ws + FMB);
  u16* fV = (u16*)(ws + 2*FMB);
  u16* Wk = (u16*)(ws + 3*FMB);
  u16* Wv = Wk + 65536;
  u16* Wo = Wv + 65536;
  u16* qs = Wo + 65536;

  hipLaunchKernelGGL(prep_all, dim3(2696), dim3(256), 0, stream,
                     features, ipw, opw, ipb, cq, fT, Wk, Wv, Wo, qs);
  hipLaunchKernelGGL(proj_kv,  dim3(HW_TOT/64), dim3(512), 0, stream,
                     fT, Wk, Wv, fK, fV);
  hipLaunchKernelGGL(fused_roi_attn, dim3(NROIS), dim3(256), 0, stream,
                     rois, balp, ipb + 512, opb, fT, fK, fV, Wo, qs, out);
}

// Round 4
// 238.349 us; speedup vs baseline: 1.0357x; 1.0357x over previous
//
#include <hip/hip_runtime.h>
#include <stdint.h>

// Problem constants
#define E_DIM 256
#define HEADS 8
#define NQ 49
#define S_TOT 196      // 14*14
#define NROIS 512
#define FH 152
#define FW 256
#define HW_TOT (FH*FW) // 38912

// LDS strides (u16 units); all row strides are multiples of 4 u16 (8B-aligned rows)
#define AT_ST 228
#define KH_ST 36
#define VT_ST 228
#define OR_ST 36
#define AS_ST 260
#define PS_ST 260

typedef unsigned short u16;
typedef short bf16x8 __attribute__((ext_vector_type(8)));
typedef float f32x4 __attribute__((ext_vector_type(4)));
typedef unsigned short us8 __attribute__((ext_vector_type(8)));

#define MFMA(a,b,c) __builtin_amdgcn_mfma_f32_16x16x32_bf16((a),(b),(c),0,0,0)

__device__ __forceinline__ u16 f2bf(float f) {
  union { float f; uint32_t u; } v; v.f = f;
  uint32_t u = v.u;
  return (u16)((u + 0x7FFFu + ((u >> 16) & 1u)) >> 16);
}
__device__ __forceinline__ float bf2f(u16 h) {
  union { uint32_t u; float f; } v; v.u = ((uint32_t)h) << 16;
  return v.f;
}
__device__ __forceinline__ bf16x8 ld_frag(const u16* p) {   // 2x ds_read_b64
  union { uint2 d[2]; bf16x8 v; } t;
  t.d[0] = *(const uint2*)(p);
  t.d[1] = *(const uint2*)(p + 4);
  return t.v;
}
__device__ __forceinline__ bf16x8 ld_frag_g(const u16* p) { // 16B global
  union { uint4 d; bf16x8 v; } t;
  t.d = *(const uint4*)(p);
  return t.v;
}
__device__ __forceinline__ ushort4 pack4(float a, float b, float c, float d) {
  ushort4 r; r.x = f2bf(a); r.y = f2bf(b); r.z = f2bf(c); r.w = f2bf(d); return r;
}

// ---------------- K0: transpose/convert features + convert weights + qs ----------------
// blocks [0,2432): fT tiles; [2432,2688): weight convert; [2688,2696): qs
__global__ __launch_bounds__(256) void prep_all(
    const float* __restrict__ f, const float* __restrict__ ipw,
    const float* __restrict__ opw, const float* __restrict__ ipb,
    const float* __restrict__ cq,
    u16* __restrict__ fT, u16* __restrict__ Wk, u16* __restrict__ Wv,
    u16* __restrict__ Wo, u16* __restrict__ qs)
{
  const int b = blockIdx.x;
  const int t = threadIdx.x;
  if (b < 2432) {
    __shared__ float tile[64][69];
    const int hw0 = (b >> 2) << 6;
    const int c0 = (b & 3) << 6;
#pragma unroll
    for (int i = 0; i < 4; ++i) {
      int c_l = (t >> 4) + (i << 4);
      int hw_l = (t & 15) << 2;
      float4 v = *(const float4*)(f + (size_t)(c0 + c_l)*HW_TOT + hw0 + hw_l);
      tile[c_l][hw_l] = v.x; tile[c_l][hw_l+1] = v.y;
      tile[c_l][hw_l+2] = v.z; tile[c_l][hw_l+3] = v.w;
    }
    __syncthreads();
    const int hw_l = t >> 2;
    const int cc = (t & 3) << 4;
    u16 tmp[16];
#pragma unroll
    for (int m = 0; m < 16; ++m) tmp[m] = f2bf(tile[cc + m][hw_l]);
    u16* dst = fT + (size_t)(hw0 + hw_l)*256 + c0 + cc;
    *(us8*)(dst)     = *(const us8*)(tmp);
    *(us8*)(dst + 8) = *(const us8*)(tmp + 8);
  } else if (b < 2688) {
    int i = ((b - 2432) << 8) + t;
    Wk[i] = f2bf(ipw[65536 + i]);
    Wv[i] = f2bf(ipw[131072 + i]);
    Wo[i] = f2bf(opw[i]);
  } else {
    int h = b - 2688;
    for (int r = 0; r < 8; ++r) {
      int o = t + 256*r;
      int qq = o >> 5, d = o & 31;
      float acc = 0.f;
      if (qq < NQ) {
        acc = ipb[h*32 + d];
        const float4* wr = (const float4*)(ipw + (size_t)(h*32 + d)*256);
        const float4* cr = (const float4*)(cq + (size_t)qq*256);
        float s = 0.f;
        for (int e = 0; e < 64; ++e) {
          float4 a = cr[e], bb = wr[e];
          s += a.x*bb.x + a.y*bb.y + a.z*bb.z + a.w*bb.w;
        }
        acc = (acc + s) * 0.17677669529663687f;   // 1/sqrt(32)
      }
      qs[h*2048 + o] = f2bf(acc);
    }
  }
}

// ---------------- K1: fK/fV = fT @ W^T, LDS-staged coalesced bf16 stores ----------------
// 512 threads, 8 waves: wave = (map = w>>2, n-quarter = w&3). 64 m x 64 n per wave.
#define CT_ST 280
__global__ __launch_bounds__(512, 4) void proj_kv(
    const u16* __restrict__ fT, const u16* __restrict__ Wk, const u16* __restrict__ Wv,
    u16* __restrict__ fK, u16* __restrict__ fV)
{
  __shared__ u16 ct[2][64][CT_ST];   // 71,680 B
  const int m0 = blockIdx.x << 6;
  const int t = threadIdx.x;
  const int lane = t & 63;
  const int w = t >> 6;
  const int g = lane >> 4, l15 = lane & 15;
  const int map = w >> 2;
  const u16* W = map ? Wv : Wk;
  const int nq = (w & 3) << 6;
  f32x4 acc[4][4];
#pragma unroll
  for (int mf = 0; mf < 4; ++mf)
#pragma unroll
    for (int nt = 0; nt < 4; ++nt) acc[mf][nt] = (f32x4){0.f,0.f,0.f,0.f};

  for (int kt = 0; kt < 8; ++kt) {
    bf16x8 a[4], bb[4];
#pragma unroll
    for (int mf = 0; mf < 4; ++mf)
      a[mf] = ld_frag_g(fT + (size_t)(m0 + (mf << 4) + l15)*256 + (kt << 5) + (g << 3));
#pragma unroll
    for (int nt = 0; nt < 4; ++nt)
      bb[nt] = ld_frag_g(W + (size_t)(nq + (nt << 4) + l15)*256 + (kt << 5) + (g << 3));
#pragma unroll
    for (int mf = 0; mf < 4; ++mf)
#pragma unroll
      for (int nt = 0; nt < 4; ++nt)
        acc[mf][nt] = MFMA(a[mf], bb[nt], acc[mf][nt]);
  }
#pragma unroll
  for (int mf = 0; mf < 4; ++mf)
#pragma unroll
    for (int nt = 0; nt < 4; ++nt)
#pragma unroll
      for (int i = 0; i < 4; ++i)
        ct[map][(mf << 4) + (g << 2) + i][nq + (nt << 4) + l15] = f2bf(acc[mf][nt][i]);
  __syncthreads();
  // coalesced write: thread -> (map2 = t>>8), row r = (t&255)>>2, 64-col chunk
  const int map2 = t >> 8;
  const int tt = t & 255;
  const int r = tt >> 2;
  const int c0 = (tt & 3) << 6;
  u16* dst = (map2 ? fV : fK) + (size_t)(m0 + r)*256 + c0;
#pragma unroll
  for (int k = 0; k < 8; ++k)
    *(us8*)(dst + (k << 3)) = *(const us8*)(&ct[map2][r][c0 + (k << 3)]);
}

// ---------------- K2: main fused kernel: 512 threads/ROI, 2 blocks/CU ----------------
// Wave-groups v=0,1 duplicate QK/softmax/PV (bitwise-identical -> idempotent LDS
// writes); sampling split across all 512 threads; out-projection split by v.
struct SMemA {
  u16 attn[64][AT_ST];    // 29,184 B  attn [q][s], cols 208..223 zeroed once
  u16 kh[208][KH_ST];     // 14,976 B  k_h [s][32d] (rows 196..207 garbage, masked)
  u16 vT[32][VT_ST];      // 14,592 B  v^T [d][s], cols 196..227 zeroed once
  u16 ore[64][OR_ST];     //  4,608 B  per-head o redistribution
};                         // 63,360 B
struct SMemC {
  u16 ast[NQ][AS_ST];     // 25,480 B
  u16 pos[NQ][PS_ST];     // 25,480 B
};                         // 50,960 B
union SMem { SMemA a; SMemC c; };   // 63,360 B -> 2 blocks/CU

__global__ __launch_bounds__(512, 4) void fused_roi_attn(
    const float* __restrict__ rois,
    const float* __restrict__ balance_p,
    const float* __restrict__ bv,       // in_proj_bias + 512
    const float* __restrict__ bout,
    const u16*  __restrict__ fT,
    const u16*  __restrict__ fK,
    const u16*  __restrict__ fV,
    const u16*  __restrict__ Woutbf,
    const u16*  __restrict__ qsPad,     // [8][64][32]
    float* __restrict__ out)            // [512][256][49]
{
  __shared__ SMem sm;
  const int tid = threadIdx.x;
  const int lane = tid & 63;
  const int w = tid >> 6;
  const int v = w >> 2;        // wave-group 0/1
  const int w2 = w & 3;        // q-row tile within group
  const int g = lane >> 4;
  const int l15 = lane & 15;
  const int n = blockIdx.x;

  // ---- ROI scalars ----
  float x1 = rois[n*5 + 1], y1r = rois[n*5 + 2], x2 = rois[n*5 + 3], y2 = rois[n*5 + 4];
  const float sc = 1.0f/16.0f;
  float sx = x1*sc - 0.5f, sy = y1r*sc - 0.5f;
  float bw = (x2 - x1)*sc*(1.0f/14.0f);
  float bh = (y2 - y1r)*sc*(1.0f/14.0f);

  // ---- per-thread sampling params: ONE (s, 16-ch half) slot per thread ----
  int pb = 0, po01 = 0, po10 = 0;
  float pw0 = 0.f, pw1 = 0.f, pw2 = 0.f, pw3 = 0.f;
  const int s_slot = tid >> 1;
  const int hf = tid & 1;
  if (tid < 2*S_TOT) {
    int s = s_slot;
    int gy = s/14, gx = s - gy*14;
    float y = sy + ((float)gy + 0.5f)*bh;
    float x = sx + ((float)gx + 0.5f)*bw;
    float valid = (y >= -1.0f && y <= (float)FH && x >= -1.0f && x <= (float)FW) ? 1.0f : 0.0f;
    float yc = fminf(fmaxf(y, 0.0f), (float)(FH-1));
    float xc = fminf(fmaxf(x, 0.0f), (float)(FW-1));
    float y0f = floorf(yc), x0f = floorf(xc);
    int y0 = (int)y0f, x0 = (int)x0f;
    float ly = yc - y0f, lx = xc - x0f;
    float hy = 1.0f - ly, hx = 1.0f - lx;
    pb   = (y0*FW + x0) << 8;
    po01 = ((x0 + 1 < FW) ? 1 : 0) << 8;
    po10 = ((y0 + 1 < FH) ? FW : 0) << 8;
    pw0 = hy*hx*valid; pw1 = hy*lx*valid;
    pw2 = ly*hx*valid; pw3 = ly*lx*valid;
  }

  // zero pads once (regions not aliased during head loop)
  for (int i = tid; i < 32*32; i += 512) sm.a.vT[i >> 5][196 + (i & 31)] = 0;
  for (int i = tid; i < 64*16; i += 512) sm.a.attn[i >> 4][208 + (i & 15)] = 0;

  float bal;
  { float bp = balance_p[0]; bal = fminf(fmaxf(bp*(1.0f/6.0f) + 0.5f, 0.0f), 1.0f); }

  // out-projection accumulators: this wave-group's 8 n-tiles (cols v*128..+127)
  f32x4 attacc[8];
#pragma unroll
  for (int i = 0; i < 8; ++i) attacc[i] = (f32x4){0.f,0.f,0.f,0.f};

  for (int h = 0; h < HEADS; ++h) {
    __syncthreads();   // T: prior-head kh/vT reads done

    // ---- sample k_h -> kh[s][32], v_h -> vT[d][s] (one slot/thread) ----
    if (tid < 2*S_TOT) {
      int base = pb + (h << 5) + (hf << 4);
      int o01 = po01, o10 = po10, o11 = o01 + o10;
      const u16* pk = fK + base;
      const u16* pv = fV + base;
      us8 k00a = *(const us8*)(pk);       us8 k00b = *(const us8*)(pk + 8);
      us8 k01a = *(const us8*)(pk + o01); us8 k01b = *(const us8*)(pk + o01 + 8);
      us8 k10a = *(const us8*)(pk + o10); us8 k10b = *(const us8*)(pk + o10 + 8);
      us8 k11a = *(const us8*)(pk + o11); us8 k11b = *(const us8*)(pk + o11 + 8);
      us8 v00a = *(const us8*)(pv);       us8 v00b = *(const us8*)(pv + 8);
      us8 v01a = *(const us8*)(pv + o01); us8 v01b = *(const us8*)(pv + o01 + 8);
      us8 v10a = *(const us8*)(pv + o10); us8 v10b = *(const us8*)(pv + o10 + 8);
      us8 v11a = *(const us8*)(pv + o11); us8 v11b = *(const us8*)(pv + o11 + 8);
      float kk[16], vv[16];
#pragma unroll
      for (int c = 0; c < 8; ++c) {
        kk[c]   = pw0*bf2f(k00a[c]) + pw1*bf2f(k01a[c]) + pw2*bf2f(k10a[c]) + pw3*bf2f(k11a[c]);
        kk[c+8] = pw0*bf2f(k00b[c]) + pw1*bf2f(k01b[c]) + pw2*bf2f(k10b[c]) + pw3*bf2f(k11b[c]);
        vv[c]   = pw0*bf2f(v00a[c]) + pw1*bf2f(v01a[c]) + pw2*bf2f(v10a[c]) + pw3*bf2f(v11a[c]);
        vv[c+8] = pw0*bf2f(v00b[c]) + pw1*bf2f(v01b[c]) + pw2*bf2f(v10b[c]) + pw3*bf2f(v11b[c]);
      }
      u16* krow = &sm.a.kh[s_slot][hf << 4];
      *(ushort4*)(krow)      = pack4(kk[0],  kk[1],  kk[2],  kk[3]);
      *(ushort4*)(krow + 4)  = pack4(kk[4],  kk[5],  kk[6],  kk[7]);
      *(ushort4*)(krow + 8)  = pack4(kk[8],  kk[9],  kk[10], kk[11]);
      *(ushort4*)(krow + 12) = pack4(kk[12], kk[13], kk[14], kk[15]);
#pragma unroll
      for (int j = 0; j < 16; ++j) sm.a.vT[(hf << 4) + j][s_slot] = f2bf(vv[j]);
    }
    __syncthreads();   // S: kh, vT ready

    // ---- logits[q=16w2+4g+i][s=16nt+l15] (duplicated across v-groups) ----
    bf16x8 aq = ld_frag_g(qsPad + (size_t)((h << 6) + (w2 << 4) + l15)*32 + (g << 3));
    f32x4 lac[13];
#pragma unroll
    for (int nt = 0; nt < 13; ++nt) {
      bf16x8 bk = ld_frag(&sm.a.kh[(nt << 4) + l15][g << 3]);
      f32x4 z = (f32x4){0.f,0.f,0.f,0.f};
      lac[nt] = MFMA(aq, bk, z);
    }
    if (l15 >= 4) {      // mask s >= 196 (overwrites any NaN from garbage kh rows)
#pragma unroll
      for (int i = 0; i < 4; ++i) lac[12][i] = -1e30f;
    }
    // ---- softmax over s ----
    float srow[4];
#pragma unroll
    for (int i = 0; i < 4; ++i) {
      float m = lac[0][i];
#pragma unroll
      for (int nt = 1; nt < 13; ++nt) m = fmaxf(m, lac[nt][i]);
#pragma unroll
      for (int off = 1; off < 16; off <<= 1) m = fmaxf(m, __shfl_xor(m, off, 64));
      float sumv = 0.f;
#pragma unroll
      for (int nt = 0; nt < 13; ++nt) {
        float p = __expf(lac[nt][i] - m);
        lac[nt][i] = p; sumv += p;
      }
#pragma unroll
      for (int off = 1; off < 16; off <<= 1) sumv += __shfl_xor(sumv, off, 64);
      srow[i] = 1.0f / sumv;
    }
    // attn writes: both v-groups write identical bits -> benign; reader wrote its own rows
#pragma unroll
    for (int nt = 0; nt < 13; ++nt)
#pragma unroll
      for (int i = 0; i < 4; ++i)
        sm.a.attn[(w2 << 4) + (g << 2) + i][(nt << 4) + l15] = f2bf(lac[nt][i]*srow[i]);

    // ---- PV: o_h = attn @ v (full K, duplicated) ----
    f32x4 o0 = (f32x4){0.f,0.f,0.f,0.f}, o1 = (f32x4){0.f,0.f,0.f,0.f};
#pragma unroll
    for (int kt = 0; kt < 7; ++kt) {
      bf16x8 ap = ld_frag(&sm.a.attn[(w2 << 4) + l15][(kt << 5) + (g << 3)]);
      bf16x8 b0 = ld_frag(&sm.a.vT[l15][(kt << 5) + (g << 3)]);
      bf16x8 b1 = ld_frag(&sm.a.vT[16 + l15][(kt << 5) + (g << 3)]);
      o0 = MFMA(ap, b0, o0);
      o1 = MFMA(ap, b1, o1);
    }
    // bias (bv commutes through softmax) + redistribute to A-frag layout
    float bv0 = bv[(h << 5) + l15];
    float bv1 = bv[(h << 5) + 16 + l15];
#pragma unroll
    for (int i = 0; i < 4; ++i) {
      sm.a.ore[(w2 << 4) + (g << 2) + i][l15]      = f2bf(o0[i] + bv0);
      sm.a.ore[(w2 << 4) + (g << 2) + i][16 + l15] = f2bf(o1[i] + bv1);
    }
    // ---- out-projection: v-group takes its 8 n-tiles ----
    bf16x8 ao = ld_frag(&sm.a.ore[(w2 << 4) + l15][g << 3]);
#pragma unroll
    for (int j = 0; j < 8; ++j) {
      int nt = (v << 3) + j;
      bf16x8 bo = ld_frag_g(Woutbf + (size_t)((nt << 4) + l15)*256 + (h << 5) + (g << 3));
      attacc[j] = MFMA(ao, bo, attacc[j]);
    }
  } // heads

  // ---- Phase C ----
  __syncthreads();   // all A-region reads done before aliasing ast/pos
#pragma unroll
  for (int j = 0; j < 8; ++j) {
    int nt = (v << 3) + j;
    float bo = bout[(nt << 4) + l15];
#pragma unroll
    for (int i = 0; i < 4; ++i) {
      int r = (w2 << 4) + (g << 2) + i;
      if (r < NQ) sm.c.ast[r][(nt << 4) + l15] = f2bf(attacc[j][i] + bo);
    }
  }
  // pos[q][c]: 4-point avg of bilinear samples at the 14x14 grid (recomputed)
  for (int it = 0; it < 7; ++it) {
    int item = tid + (it << 9);
    if (item < NQ*64) {
      int q = item >> 6, cg = item & 63;
      int oy = q/7, ox = q - oy*7;
      float a0 = 0.f, a1 = 0.f, a2 = 0.f, a3 = 0.f;
#pragma unroll
      for (int jj = 0; jj < 2; ++jj)
#pragma unroll
        for (int ii = 0; ii < 2; ++ii) {
          int gy = (oy << 1) + jj, gx = (ox << 1) + ii;
          float y = sy + ((float)gy + 0.5f)*bh;
          float x = sx + ((float)gx + 0.5f)*bw;
          float valid = (y >= -1.0f && y <= (float)FH && x >= -1.0f && x <= (float)FW) ? 1.0f : 0.0f;
          float yc = fminf(fmaxf(y, 0.0f), (float)(FH-1));
          float xc = fminf(fmaxf(x, 0.0f), (float)(FW-1));
          float y0f = floorf(yc), x0f = floorf(xc);
          int y0 = (int)y0f, x0 = (int)x0f;
          int o01 = ((x0 + 1 < FW) ? 1 : 0) << 8;
          int o10 = ((y0 + 1 < FH) ? FW : 0) << 8;
          float ly = yc - y0f, lx = xc - x0f;
          float hy = 1.0f - ly, hx = 1.0f - lx;
          float u0 = hy*hx*valid, u1 = hy*lx*valid, u2 = ly*hx*valid, u3 = ly*lx*valid;
          const u16* pt = fT + (((size_t)(y0*FW + x0)) << 8) + (cg << 2);
          ushort4 c00 = *(const ushort4*)(pt);
          ushort4 c01 = *(const ushort4*)(pt + o01);
          ushort4 c10 = *(const ushort4*)(pt + o10);
          ushort4 c11 = *(const ushort4*)(pt + o10 + o01);
          a0 += u0*bf2f(c00.x) + u1*bf2f(c01.x) + u2*bf2f(c10.x) + u3*bf2f(c11.x);
          a1 += u0*bf2f(c00.y) + u1*bf2f(c01.y) + u2*bf2f(c10.y) + u3*bf2f(c11.y);
          a2 += u0*bf2f(c00.z) + u1*bf2f(c01.z) + u2*bf2f(c10.z) + u3*bf2f(c11.z);
          a3 += u0*bf2f(c00.w) + u1*bf2f(c01.w) + u2*bf2f(c10.w) + u3*bf2f(c11.w);
        }
      *(ushort4*)(&sm.c.pos[q][cg << 2]) = pack4(0.25f*a0, 0.25f*a1, 0.25f*a2, 0.25f*a3);
    }
  }
  __syncthreads();
  float ibal = 1.0f - bal;
  float* outp = out + (size_t)n*(E_DIM*NQ);
  for (int j = 0; j < 25; ++j) {
    int idx = (j << 9) + tid;
    if (idx < E_DIM*NQ) {
      int eo = idx/49;
      int q  = idx - eo*49;
      outp[idx] = bal*bf2f(sm.c.pos[q][eo]) + ibal*bf2f(sm.c.ast[q][eo]);
    }
  }
}

// ---------------- launcher ----------------
// ws: fT | fK | fV (19,922,944 B each) | Wk | Wv | Wo (131,072 each) | qs 32,768
extern "C" void kernel_launch(void* const* d_in, const int* in_sizes, int n_in,
                              void* d_out, int out_size, void* d_ws, size_t ws_size,
                              hipStream_t stream) {
  const float* features = (const float*)d_in[0];
  const float* rois     = (const float*)d_in[1];
  const float* cq       = (const float*)d_in[2];
  const float* ipw      = (const float*)d_in[3];
  const float* ipb      = (const float*)d_in[4];
  const float* opw      = (const float*)d_in[5];
  const float* opb      = (const float*)d_in[6];
  const float* balp     = (const float*)d_in[7];
  float* out = (float*)d_out;

  char* ws = (char*)d_ws;
  const size_t FMB = (size_t)HW_TOT*256*2;   // 19,922,944
  u16* fT = (u16*)ws;
  u16* fK = (u16*)(ws + FMB);
  u16* fV = (u16*)(ws + 2*FMB);
  u16* Wk = (u16*)(ws + 3*FMB);
  u16* Wv = Wk + 65536;
  u16* Wo = Wv + 65536;
  u16* qs = Wo + 65536;

  hipLaunchKernelGGL(prep_all, dim3(2696), dim3(256), 0, stream,
                     features, ipw, opw, ipb, cq, fT, Wk, Wv, Wo, qs);
  hipLaunchKernelGGL(proj_kv,  dim3(HW_TOT/64), dim3(512), 0, stream,
                     fT, Wk, Wv, fK, fV);
  hipLaunchKernelGGL(fused_roi_attn, dim3(NROIS), dim3(512), 0, stream,
                     rois, balp, ipb + 512, opb, fT, fK, fV, Wo, qs, out);
}